// Round 10
// baseline (1133.007 us; speedup 1.0000x reference)
//
#include <hip/hip_runtime.h>
#include <hip/hip_bf16.h>
#include <stdint.h>

#define BB 64
#define SS 2048
#define TT 128
#define GRP 6              // renorm interval (growth < e^44 between renorms, f32/bf16 max e^88)

typedef __bf16 bf16x8 __attribute__((ext_vector_type(8)));
typedef float  f32x4  __attribute__((ext_vector_type(4)));

// Raw workgroup barrier that does NOT drain vmcnt (LDS ordering only).
__device__ __forceinline__ void wg_barrier_lds() {
    asm volatile("" ::: "memory");
    __builtin_amdgcn_s_waitcnt(0xc07f);   // lgkmcnt(0), vmcnt/expcnt no-wait
    __builtin_amdgcn_s_barrier();
    asm volatile("" ::: "memory");
}

// ---- bool-layout detection: mask[0,0] is always true (len >= 1024) ----
__device__ __forceinline__ int detect_mode(const void* maskp) {
    uint32_t w0 = ((const uint32_t*)maskp)[0];
    if (w0 == 1u) return 0;
    if (w0 == 0x3F800000u) return 2;
    if (w0 == 0x3F803F80u) return 3;
    return 1;
}
__device__ __forceinline__ int mask_at(const void* maskp, int mode, size_t idx) {
    if (mode == 0) return ((const int*)maskp)[idx] != 0;
    if (mode == 1) return ((const unsigned char*)maskp)[idx] != 0;
    if (mode == 2) return ((const float*)maskp)[idx] != 0.f;
    return ((const unsigned short*)maskp)[idx] != 0;
}

struct EndSh {
    __bf16 uS[2][TT];          // 512 B, double-buffered state (wave-0-private in main loop)
    float  wred[4];
    int    redi[8];
    double redd[8];
    int    redc[8];
    float  Minit;
};
struct MidSh {
    // transfer matrix, col-major, XOR-swizzled: elem k of col n at n*128 + (k ^ ((n&7)<<3)).
    __bf16 T[2][128 * 128];    // 65,536 B (the 64 KiB static limit)
};
union ShU { EndSh e; MidSh m; };

// ---- 4-way split per batch ----
// blocks [0,64):    fwd matvec  alpha_0 -> alpha_q1          (A = E^T)
// blocks [64,128):  bwd matvec  delta_{len-1} -> gamma_q3    (A = E)
// blocks [128,256): transfer GEMM chain (2 per batch)
// combine: z = Cf+Cb+K1+K2 + log( gamma^T T_B T_A alpha ), f64.
//
// END CHAINS ARE SINGLE-WAVE (round 10): the whole 128x128 E-frag set is 128
// VGPR, affordable under the 256/wave cap (512-thread block = 2 waves/SIMD).
// One wave does the full matvec -> the u exchange is a wave-private LDS
// round-trip (ds_write -> lgkmcnt -> ds_read), NO s_barrier in the loop.
// Round 9's 4-wave step paid a block-wide barrier + cross-SIMD LDS latency
// every step (~460 ns); this removes ~half of it.
//
// RULE-#20: every private array is indexed ONLY with compile-time constants
// (after unroll). The rounds-3..7 1-GB scratch bug came from ONE runtime
// array index. Do not reintroduce.
__global__ __launch_bounds__(512, 1) void scan_kernel(
    const float* __restrict__ em, const void* __restrict__ maskp,
    const int* __restrict__ tags, const void* __restrict__ forb,
    const float* __restrict__ trans,
    const float* __restrict__ startt, const float* __restrict__ endt,
    double* __restrict__ CdW, float* __restrict__ pendW,
    float* __restrict__ uMW, double* __restrict__ lsW,
    unsigned short* __restrict__ Tws, double* __restrict__ postout)
{
    const int t = threadIdx.x;
    const int w = t >> 6;          // wave 0..7
    const int lane = t & 63;
    const int q = lane >> 4;       // quad 0..3
    const int c = lane & 15;       // MFMA n-column
    const int bid = blockIdx.x;

    __shared__ __align__(16) ShU sh;

    const int mode = detect_mode(maskp);

    const bool isEnd = (bid < 2 * BB);
    const bool isF = (bid < BB);
    const int seg = isEnd ? 0 : (bid - 2 * BB);
    const int b = isEnd ? (isF ? bid : bid - BB) : (seg >> 1);
    const int half = seg & 1;

    // ---- length of this batch (contiguous mask prefix) ----
    {
        int cnt = 0;
        for (int s = t; s < SS; s += 512) cnt += mask_at(maskp, mode, (size_t)b * SS + s);
        #pragma unroll
        for (int off = 32; off >= 1; off >>= 1) cnt += __shfl_xor(cnt, off);
        if (lane == 0) sh.e.redi[w] = cnt;
    }
    __syncthreads();
    int len = 0;
    #pragma unroll
    for (int i = 0; i < 8; ++i) len += sh.e.redi[i];
    __syncthreads();   // everyone done reading redi before LDS reuse

    // ---- split points: t_e ~0.25us (1-wave), t_m ~1.25us -> M = 9% of (len-1) ----
    const int M  = ((len - 1) * 9) / 100;          // mid segment steps (each)
    const int E1 = ((len - 1) - 2 * M + 1) >> 1;   // fwd steps
    const int q1 = E1;
    const int q2 = q1 + M;
    const int q3 = q2 + M;
    const int E2 = (len - 1) - q3;                 // bwd steps

    const float* emB = em + (size_t)b * SS * TT;

    if (isEnd) {
        // =================== END SEGMENTS: single-wave matvec chain ===================
        const int steps = isF ? q1 : E2;
        const int curF = steps & 1;                // final dbuf index (cur toggles each step)

        // init: fwd u0 = exp(start + em[0] - M0); bwd d_{len-1} = exp(end + em[len-1] - M0)
        if (t < 16) {
            const float* base = isF ? startt : endt;
            const float* emI  = emB + (isF ? 0 : (size_t)(len - 1) * TT);
            float a[8]; float mx = -1e30f;
            #pragma unroll
            for (int jj = 0; jj < 8; ++jj) {
                int j = t * 8 + jj;
                a[jj] = base[j] + emI[j];
                mx = fmaxf(mx, a[jj]);
            }
            mx = fmaxf(mx, __shfl_xor(mx, 1)); mx = fmaxf(mx, __shfl_xor(mx, 2));
            mx = fmaxf(mx, __shfl_xor(mx, 4)); mx = fmaxf(mx, __shfl_xor(mx, 8));
            union { __bf16 h[8]; uint4 v; } pk;
            #pragma unroll
            for (int jj = 0; jj < 8; ++jj) pk.h[jj] = (__bf16)__expf(a[jj] - mx);
            *(uint4*)&sh.e.uS[0][t * 8] = pk.v;
            if (t == 0) sh.e.Minit = mx;
        }
        __syncthreads();

        if (w == 0) {
            // Full A-frags in registers: 8 m-tiles x 4 k-tiles (128 VGPR).
            // fwd (A=E^T): af[mt][kt][jj] = E[32kt+8q+jj][16mt+c]
            // bwd (A=E):   af[mt][kt][jj] = E[16mt+c][32kt+8q+jj]
            bf16x8 af[8][4];
            #pragma unroll
            for (int mt = 0; mt < 8; ++mt) {
                #pragma unroll
                for (int kt = 0; kt < 4; ++kt) {
                    #pragma unroll
                    for (int jj = 0; jj < 8; ++jj) {
                        int row = isF ? (32 * kt + 8 * q + jj) : (16 * mt + c);
                        int col = isF ? (16 * mt + c) : (32 * kt + 8 * q + jj);
                        size_t idx = (size_t)row * TT + col;
                        af[mt][kt][jj] = mask_at(forb, mode, idx) ? (__bf16)0.f
                                                                  : (__bf16)__expf(trans[idx]);
                    }
                }
            }

            double Cd = (double)sh.e.Minit;
            float pending = 1.0f;
            int cur = 0;
            int rc = 0;

            // prefetch slot: em row -> exp -> bf16-packed scales (uint2 = rows r0..r3 of one mt)
            auto ldsc = [&](int k, int mi) -> uint2 {
                int kk = isF ? (1 + k) : (len - 2 - k);
                kk = kk < SS ? kk : SS - 1;
                kk = kk > 0 ? kk : 0;
                float4 e = *(const float4*)(emB + (size_t)kk * TT + 16 * mi + 4 * q);
                union { __bf16 h[4]; uint2 v; } u;
                u.h[0] = (__bf16)__expf(e.x); u.h[1] = (__bf16)__expf(e.y);
                u.h[2] = (__bf16)__expf(e.z); u.h[3] = (__bf16)__expf(e.w);
                return u.v;
            };

            // one step: 4 LDS b128 reads (broadcast) -> 32 MFMA -> scale -> pack -> 8 LDS b64 writes
            auto estep = [&](uint2 s0, uint2 s1, uint2 s2, uint2 s3,
                             uint2 s4, uint2 s5, uint2 s6, uint2 s7, bool scaleEm) {
                const uint2 sv[8] = {s0, s1, s2, s3, s4, s5, s6, s7};  // static idx only
                const __bf16* ub = &sh.e.uS[cur][0];

                f32x4 acc[8];
                #pragma unroll
                for (int mt = 0; mt < 8; ++mt) acc[mt] = (f32x4){0.f, 0.f, 0.f, 0.f};
                #pragma unroll
                for (int kt = 0; kt < 4; ++kt) {
                    bf16x8 bfk = *(const bf16x8*)(ub + 32 * kt + 8 * q);
                    #pragma unroll
                    for (int mt = 0; mt < 8; ++mt)
                        acc[mt] = __builtin_amdgcn_mfma_f32_16x16x32_bf16(af[mt][kt], bfk, acc[mt], 0, 0, 0);
                }

                ++rc;
                const bool ren = (rc == GRP);
                if (ren) rc = 0;
                const float pq = pending;

                float vmax = 0.f;
                __bf16* un = &sh.e.uS[cur ^ 1][0];
                #pragma unroll
                for (int mt = 0; mt < 8; ++mt) {
                    union { __bf16 h[4]; uint2 v; } su; su.v = sv[mt];
                    float s0f = scaleEm ? (float)su.h[0] : 1.0f;
                    float s1f = scaleEm ? (float)su.h[1] : 1.0f;
                    float s2f = scaleEm ? (float)su.h[2] : 1.0f;
                    float s3f = scaleEm ? (float)su.h[3] : 1.0f;
                    float v0 = acc[mt][0] * s0f * pq;
                    float v1 = acc[mt][1] * s1f * pq;
                    float v2 = acc[mt][2] * s2f * pq;
                    float v3 = acc[mt][3] * s3f * pq;
                    vmax = fmaxf(vmax, fmaxf(fmaxf(v0, v1), fmaxf(v2, v3)));
                    union { __bf16 h[4]; uint2 v; } pk;
                    pk.h[0] = (__bf16)v0; pk.h[1] = (__bf16)v1;
                    pk.h[2] = (__bf16)v2; pk.h[3] = (__bf16)v3;
                    if (c == 0) *(uint2*)(un + 16 * mt + 4 * q) = pk.v;
                }
                if (ren) {  // reduce over q only (all c identical)
                    vmax = fmaxf(vmax, __shfl_xor(vmax, 16));
                    vmax = fmaxf(vmax, __shfl_xor(vmax, 32));
                    pending = 1.0f / vmax;
                    Cd += (double)__logf(vmax);
                } else {
                    pending = 1.0f;
                }
                cur ^= 1;
            };

            // 2-unrolled loop, 2-step-deep em prefetch in NAMED slots (rule #20)
            uint2 sA0 = ldsc(0, 0), sA1 = ldsc(0, 1), sA2 = ldsc(0, 2), sA3 = ldsc(0, 3),
                  sA4 = ldsc(0, 4), sA5 = ldsc(0, 5), sA6 = ldsc(0, 6), sA7 = ldsc(0, 7);
            uint2 sB0 = ldsc(1, 0), sB1 = ldsc(1, 1), sB2 = ldsc(1, 2), sB3 = ldsc(1, 3),
                  sB4 = ldsc(1, 4), sB5 = ldsc(1, 5), sB6 = ldsc(1, 6), sB7 = ldsc(1, 7);
            int k = 0;
            while (k + 2 <= steps) {
                estep(sA0, sA1, sA2, sA3, sA4, sA5, sA6, sA7, isF || (k != steps - 1));
                sA0 = ldsc(k + 2, 0); sA1 = ldsc(k + 2, 1); sA2 = ldsc(k + 2, 2); sA3 = ldsc(k + 2, 3);
                sA4 = ldsc(k + 2, 4); sA5 = ldsc(k + 2, 5); sA6 = ldsc(k + 2, 6); sA7 = ldsc(k + 2, 7);
                estep(sB0, sB1, sB2, sB3, sB4, sB5, sB6, sB7, isF || (k + 1 != steps - 1));
                sB0 = ldsc(k + 3, 0); sB1 = ldsc(k + 3, 1); sB2 = ldsc(k + 3, 2); sB3 = ldsc(k + 3, 3);
                sB4 = ldsc(k + 3, 4); sB5 = ldsc(k + 3, 5); sB6 = ldsc(k + 3, 6); sB7 = ldsc(k + 3, 7);
                k += 2;
            }
            if (k < steps)
                estep(sA0, sA1, sA2, sA3, sA4, sA5, sA6, sA7, isF || (k != steps - 1));

            if (lane == 0) { CdW[(isF ? 0 : BB) + b] = Cd; pendW[(isF ? 0 : BB) + b] = pending; }
        }
        __syncthreads();   // uS[curF] now coherent for all waves

        // ---- dump state (fwd: alpha_q1 scaled; bwd: gamma_q3 scaled) ----
        if (t < TT) uMW[(size_t)(isF ? 0 : BB) * TT + (size_t)b * TT + t] = (float)sh.e.uS[curF][t];

        // ---- posterior path score (fwd blocks only; 512 threads strided) ----
        if (isF) {
            const int* tg = tags + (size_t)b * SS;
            double local = 0.0; int fcnt = 0;
            for (int kk = 1 + t; kk < len; kk += 512) {
                int tp = tg[kk - 1], tc = tg[kk];
                if (mask_at(forb, mode, (size_t)tp * TT + tc)) fcnt++;
                else local += (double)trans[tp * TT + tc];
                local += (double)emB[(size_t)kk * TT + tc];
            }
            if (t == 0) {
                local += (double)startt[tg[0]] + (double)emB[tg[0]];
                local += (double)endt[tg[len - 1]];
            }
            #pragma unroll
            for (int off = 32; off >= 1; off >>= 1) {
                local += __shfl_xor(local, off);
                fcnt  += __shfl_xor(fcnt, off);
            }
            if (lane == 0) { sh.e.redd[w] = local; sh.e.redc[w] = fcnt; }
            __syncthreads();
            if (t == 0) {
                double tot = 0.0; int fc = 0;
                #pragma unroll
                for (int i = 0; i < 8; ++i) { tot += sh.e.redd[i]; fc += sh.e.redc[i]; }
                postout[b] = tot - 100000.0 * (double)fc;
            }
        }
    } else {
        // =================== MID SEGMENTS (unchanged from round 9, proven) ===================
        const int wr = w >> 2;
        const int wc = w & 3;
        const int ks = half ? q2 : q1;     // steps consume em rows ks+1 .. ks+M
        const int steps = M;
        const int col0 = 32 * wc + c;
        const int col1 = col0 + 16;
        const int base0 = col0 * 128;
        const int base1 = col1 * 128;
        const int sw = (c & 7) << 3;
        const int rowq = 4 * q;

        // A = E^T: af[mi][kt][jj] = E[32kt+8q+jj][16*(4wr+mi)+c]
        bf16x8 af[4][4];
        #pragma unroll
        for (int mi = 0; mi < 4; ++mi) {
            #pragma unroll
            for (int kt = 0; kt < 4; ++kt) {
                #pragma unroll
                for (int jj = 0; jj < 8; ++jj) {
                    size_t idx = (size_t)(32 * kt + 8 * q + jj) * TT + (16 * (4 * wr + mi) + c);
                    af[mi][kt][jj] = mask_at(forb, mode, idx) ? (__bf16)0.f
                                                              : (__bf16)__expf(trans[idx]);
                }
            }
        }

        // identity init of T[0] (swizzled)
        for (int p = t; p < 8192; p += 512) {
            int n  = p >> 6;
            int k2 = (p & 63) * 2;
            unsigned int v = (k2 == n ? 0x3F80u : 0u) | (k2 + 1 == n ? 0x3F800000u : 0u);
            *(unsigned int*)&sh.m.T[0][n * 128 + (k2 ^ ((n & 7) << 3))] = v;
        }
        __syncthreads();

        double Cdc0 = 0.0, Cdc1 = 0.0;
        int cur = 0;
        int rc = 0;

        auto lde = [&](int s, int mi) -> float4 {
            int kk = ks + 1 + s; kk = kk < SS ? kk : SS - 1;
            return *(const float4*)(emB + (size_t)kk * TT + 16 * (4 * wr + mi) + rowq);
        };

        auto midstep = [&](float4 ev0, float4 ev1, float4 ev2, float4 ev3) {
            const float4 ev[4] = {ev0, ev1, ev2, ev3};   // static-index only below
            const __bf16* Tc = &sh.m.T[cur][0];
            bf16x8 bf0[4], bf1[4];
            #pragma unroll
            for (int kt = 0; kt < 4; ++kt) {
                int eo = (32 * kt + 8 * q) ^ sw;
                bf0[kt] = *(const bf16x8*)(Tc + base0 + eo);
                bf1[kt] = *(const bf16x8*)(Tc + base1 + eo);
            }

            bool ren;
            if (rc == GRP) { ren = true; rc = 0; } else ren = false;
            ++rc;

            float pend0 = 1.0f, pend1 = 1.0f;
            if (ren) {
                float m0 = 0.f, m1 = 0.f;
                #pragma unroll
                for (int kt = 0; kt < 4; ++kt) {
                    #pragma unroll
                    for (int jj = 0; jj < 8; ++jj) {
                        m0 = fmaxf(m0, (float)bf0[kt][jj]);
                        m1 = fmaxf(m1, (float)bf1[kt][jj]);
                    }
                }
                m0 = fmaxf(m0, __shfl_xor(m0, 16)); m0 = fmaxf(m0, __shfl_xor(m0, 32));
                m1 = fmaxf(m1, __shfl_xor(m1, 16)); m1 = fmaxf(m1, __shfl_xor(m1, 32));
                pend0 = 1.0f / m0; pend1 = 1.0f / m1;
                Cdc0 += (double)__logf(m0); Cdc1 += (double)__logf(m1);
            }

            f32x4 acc[4][2];
            #pragma unroll
            for (int mi = 0; mi < 4; ++mi) {
                acc[mi][0] = (f32x4){0.f, 0.f, 0.f, 0.f};
                acc[mi][1] = (f32x4){0.f, 0.f, 0.f, 0.f};
            }
            #pragma unroll
            for (int kt = 0; kt < 4; ++kt) {
                #pragma unroll
                for (int mi = 0; mi < 4; ++mi)
                    acc[mi][0] = __builtin_amdgcn_mfma_f32_16x16x32_bf16(af[mi][kt], bf0[kt], acc[mi][0], 0, 0, 0);
                #pragma unroll
                for (int mi = 0; mi < 4; ++mi)
                    acc[mi][1] = __builtin_amdgcn_mfma_f32_16x16x32_bf16(af[mi][kt], bf1[kt], acc[mi][1], 0, 0, 0);
            }

            __bf16* Tn = &sh.m.T[cur ^ 1][0];
            #pragma unroll
            for (int mi = 0; mi < 4; ++mi) {
                float s0 = __expf(ev[mi].x), s1 = __expf(ev[mi].y);
                float s2 = __expf(ev[mi].z), s3 = __expf(ev[mi].w);
                const int row = 16 * (4 * wr + mi) + rowq;
                const int eo = row ^ sw;
                union { __bf16 h[4]; uint2 u; } pk0, pk1;
                pk0.h[0] = (__bf16)(acc[mi][0][0] * s0 * pend0);
                pk0.h[1] = (__bf16)(acc[mi][0][1] * s1 * pend0);
                pk0.h[2] = (__bf16)(acc[mi][0][2] * s2 * pend0);
                pk0.h[3] = (__bf16)(acc[mi][0][3] * s3 * pend0);
                pk1.h[0] = (__bf16)(acc[mi][1][0] * s0 * pend1);
                pk1.h[1] = (__bf16)(acc[mi][1][1] * s1 * pend1);
                pk1.h[2] = (__bf16)(acc[mi][1][2] * s2 * pend1);
                pk1.h[3] = (__bf16)(acc[mi][1][3] * s3 * pend1);
                *(uint2*)(Tn + base0 + eo) = pk0.u;
                *(uint2*)(Tn + base1 + eo) = pk1.u;
            }
            wg_barrier_lds();
            cur ^= 1;
        };

        float4 eA0 = lde(0, 0), eA1 = lde(0, 1), eA2 = lde(0, 2), eA3 = lde(0, 3);
        float4 eB0 = lde(1, 0), eB1 = lde(1, 1), eB2 = lde(1, 2), eB3 = lde(1, 3);
        int s = 0;
        while (s + 2 <= steps) {
            midstep(eA0, eA1, eA2, eA3);
            eA0 = lde(s + 2, 0); eA1 = lde(s + 2, 1); eA2 = lde(s + 2, 2); eA3 = lde(s + 2, 3);
            midstep(eB0, eB1, eB2, eB3);
            eB0 = lde(s + 3, 0); eB1 = lde(s + 3, 1); eB2 = lde(s + 3, 2); eB3 = lde(s + 3, 3);
            s += 2;
        }
        if (s < steps) midstep(eA0, eA1, eA2, eA3);

        __syncthreads();
        if (wr == 0 && q == 0) {
            lsW[(size_t)seg * 128 + col0] = Cdc0;
            lsW[(size_t)seg * 128 + col1] = Cdc1;
        }
        for (int p = t; p < 8192; p += 512) {
            int n  = p >> 6;
            int k2 = (p & 63) * 2;
            unsigned int v = *(const unsigned int*)&sh.m.T[cur][n * 128 + (k2 ^ ((n & 7) << 3))];
            *(unsigned int*)&Tws[(size_t)seg * 16384 + (size_t)n * 128 + k2] = v;
        }
    }
}

// ---- combine: z[b] = Cf + lpf + K1 + K2 + Cb + lpb + log( sum_i s_i*gamma_i ) ----
__global__ __launch_bounds__(128) void comb_kernel(
    const double* __restrict__ CdW, const float* __restrict__ pendW,
    const float* __restrict__ uMW, const double* __restrict__ lsW,
    const unsigned short* __restrict__ Tws, double* __restrict__ zarr)
{
    const int b = blockIdx.x, i = threadIdx.x;
    __shared__ double wv[128];
    __shared__ double red[128];

    double lsA = lsW[(size_t)(2 * b) * 128 + i];
    float  xf  = uMW[(size_t)b * 128 + i];
    double a1  = (xf > 0.f) ? lsA + log((double)xf) : -1e300;
    red[i] = a1; __syncthreads();
    for (int sdel = 64; sdel >= 1; sdel >>= 1) {
        if (i < sdel) red[i] = fmax(red[i], red[i + sdel]);
        __syncthreads();
    }
    double K1 = red[0]; __syncthreads();
    wv[i] = (xf > 0.f) ? exp(a1 - K1) : 0.0; __syncthreads();

    const unsigned short* TA = Tws + (size_t)(2 * b) * 16384;
    double y = 0.0;
    for (int n = 0; n < 128; ++n) {
        unsigned int u = ((unsigned int)TA[(size_t)n * 128 + i]) << 16;
        y += (double)__uint_as_float(u) * wv[n];
    }
    __syncthreads();

    double lsB = lsW[(size_t)(2 * b + 1) * 128 + i];
    double a2  = (y > 0.0) ? lsB + log(y) : -1e300;
    red[i] = a2; __syncthreads();
    for (int sdel = 64; sdel >= 1; sdel >>= 1) {
        if (i < sdel) red[i] = fmax(red[i], red[i + sdel]);
        __syncthreads();
    }
    double K2 = red[0]; __syncthreads();
    wv[i] = (y > 0.0) ? exp(a2 - K2) : 0.0; __syncthreads();

    const unsigned short* TB = Tws + (size_t)(2 * b + 1) * 16384;
    double s = 0.0;
    for (int n = 0; n < 128; ++n) {
        unsigned int u = ((unsigned int)TB[(size_t)n * 128 + i]) << 16;
        s += (double)__uint_as_float(u) * wv[n];
    }
    double g = (double)uMW[(size_t)(BB + b) * 128 + i];
    red[i] = s * g; __syncthreads();
    for (int sdel = 64; sdel >= 1; sdel >>= 1) {
        if (i < sdel) red[i] += red[i + sdel];
        __syncthreads();
    }
    if (i == 0) {
        zarr[b] = CdW[b] + log((double)pendW[b])
                + CdW[BB + b] + log((double)pendW[BB + b])
                + K1 + K2 + log(red[0]);
    }
}

// ---- nll = mean(post) - mean(z) ----
__global__ void fin_kernel(const double* __restrict__ z, const double* __restrict__ post,
                           float* __restrict__ out) {
    int t = threadIdx.x; // 64 threads, 1 wave
    double pv = post[t];
    double zv = z[t];
    #pragma unroll
    for (int off = 32; off >= 1; off >>= 1) {
        pv += __shfl_xor(pv, off);
        zv += __shfl_xor(zv, off);
    }
    if (t == 0) out[0] = (float)((pv - zv) / (double)BB);
}

extern "C" void kernel_launch(void* const* d_in, const int* in_sizes, int n_in,
                              void* d_out, int out_size, void* d_ws, size_t ws_size,
                              hipStream_t stream) {
    const float* em     = (const float*)d_in[0];
    const void*  maskp  = d_in[1];
    const int*   tags   = (const int*)d_in[2];
    const void*  forb   = d_in[3];
    const float* trans  = (const float*)d_in[4];
    const float* startt = (const float*)d_in[5];
    const float* endt   = (const float*)d_in[6];

    // workspace: ~4.4 MB (layout proven in round 3)
    double* post  = (double*)d_ws;                     // 64
    double* zarr  = post + BB;                         // 64
    double* CdW   = zarr + BB;                         // 128 (fwd | bwd)
    double* lsW   = CdW + 2 * BB;                      // 128 segs x 128 cols
    float*  pendW = (float*)(lsW + 128 * 128);         // 128
    float*  uMW   = pendW + 2 * BB;                    // 128 x 128 (fwd states | bwd states)
    unsigned short* Tws = (unsigned short*)(uMW + 128 * 128); // 128 segs x 128 x 128 bf16

    scan_kernel<<<4 * BB, 512, 0, stream>>>(em, maskp, tags, forb, trans, startt, endt,
                                            CdW, pendW, uMW, lsW, Tws, post);
    comb_kernel<<<BB, 128, 0, stream>>>(CdW, pendW, uMW, lsW, Tws, zarr);
    fin_kernel<<<1, 64, 0, stream>>>(zarr, post, (float*)d_out);
}

// Round 11
// 1101.859 us; speedup vs baseline: 1.0283x; 1.0283x over previous
//
#include <hip/hip_runtime.h>
#include <hip/hip_bf16.h>
#include <stdint.h>

#define BB 64
#define SS 2048
#define TT 128
#define GRP 6              // renorm interval (growth < e^44 between renorms, f32/bf16 max e^88)

typedef __bf16 bf16x8 __attribute__((ext_vector_type(8)));
typedef float  f32x4  __attribute__((ext_vector_type(4)));

// Raw workgroup barrier that does NOT drain vmcnt (LDS ordering only).
__device__ __forceinline__ void wg_barrier_lds() {
    asm volatile("" ::: "memory");
    __builtin_amdgcn_s_waitcnt(0xc07f);   // lgkmcnt(0), vmcnt/expcnt no-wait
    __builtin_amdgcn_s_barrier();
    asm volatile("" ::: "memory");
}

// ---- bool-layout detection: mask[0,0] is always true (len >= 1024) ----
__device__ __forceinline__ int detect_mode(const void* maskp) {
    uint32_t w0 = ((const uint32_t*)maskp)[0];
    if (w0 == 1u) return 0;
    if (w0 == 0x3F800000u) return 2;
    if (w0 == 0x3F803F80u) return 3;
    return 1;
}
__device__ __forceinline__ int mask_at(const void* maskp, int mode, size_t idx) {
    if (mode == 0) return ((const int*)maskp)[idx] != 0;
    if (mode == 1) return ((const unsigned char*)maskp)[idx] != 0;
    if (mode == 2) return ((const float*)maskp)[idx] != 0.f;
    return ((const unsigned short*)maskp)[idx] != 0;
}

struct EndSh {
    __bf16 uS[2][TT];          // 512 B, double-buffered state (wave-0-private in main loop)
    float  wred[4];
    int    redi[8];
    double redd[8];
    int    redc[8];
    float  Minit;
};
struct MidSh {
    // transfer matrix, col-major, XOR-swizzled: elem k of col n at n*128 + (k ^ ((n&7)<<3)).
    __bf16 T[2][128 * 128];    // 65,536 B (the 64 KiB static limit)
};
union ShU { EndSh e; MidSh m; };

// ---- 4-way split per batch ----
// blocks [0,64):    fwd matvec  alpha_0 -> alpha_q1          (A = E^T)
// blocks [64,128):  bwd matvec  delta_{len-1} -> gamma_q3    (A = E)
// blocks [128,256): transfer GEMM chain (2 per batch)
// combine: z = Cf+Cb+K1+K2 + log( gamma^T T_B T_A alpha ), f64.
//
// REGISTER BUDGET (round 11): amdgpu_waves_per_eu(2,2) pins the allocator to
// 2 waves/EU -> 256 VGPR/wave. Round 10 omitted it; the allocator targeted
// 4 waves/EU (VGPR_Count=128) and cache-spilled the end path's af[8][4]
// (~invisible in FETCH/WRITE since the scratch set is L1/L2-resident, but
// ~L2-latency reloads every step tripled the end step). __launch_bounds__'
// 2nd arg only sets the MIN waves/EU — it does not stop the optimizer from
// targeting more waves with fewer registers; waves_per_eu(max=2) does.
//
// END CHAINS ARE SINGLE-WAVE: whole 128x128 E-frag set in registers (128
// VGPR); the u exchange is a wave-private LDS round-trip (ds_write ->
// lgkmcnt -> ds_read), NO s_barrier in the loop. Numerics of this exact
// structure verified round 10 (passed, absmax 0.0).
//
// RULE-#20: every private array is indexed ONLY with compile-time constants
// (after unroll). The rounds-3..7 1-GB scratch bug came from ONE runtime
// array index. Do not reintroduce.
__global__ __attribute__((amdgpu_waves_per_eu(2, 2))) __launch_bounds__(512)
void scan_kernel(
    const float* __restrict__ em, const void* __restrict__ maskp,
    const int* __restrict__ tags, const void* __restrict__ forb,
    const float* __restrict__ trans,
    const float* __restrict__ startt, const float* __restrict__ endt,
    double* __restrict__ CdW, float* __restrict__ pendW,
    float* __restrict__ uMW, double* __restrict__ lsW,
    unsigned short* __restrict__ Tws, double* __restrict__ postout)
{
    const int t = threadIdx.x;
    const int w = t >> 6;          // wave 0..7
    const int lane = t & 63;
    const int q = lane >> 4;       // quad 0..3
    const int c = lane & 15;       // MFMA n-column
    const int bid = blockIdx.x;

    __shared__ __align__(16) ShU sh;

    const int mode = detect_mode(maskp);

    const bool isEnd = (bid < 2 * BB);
    const bool isF = (bid < BB);
    const int seg = isEnd ? 0 : (bid - 2 * BB);
    const int b = isEnd ? (isF ? bid : bid - BB) : (seg >> 1);
    const int half = seg & 1;

    // ---- length of this batch (contiguous mask prefix) ----
    {
        int cnt = 0;
        for (int s = t; s < SS; s += 512) cnt += mask_at(maskp, mode, (size_t)b * SS + s);
        #pragma unroll
        for (int off = 32; off >= 1; off >>= 1) cnt += __shfl_xor(cnt, off);
        if (lane == 0) sh.e.redi[w] = cnt;
    }
    __syncthreads();
    int len = 0;
    #pragma unroll
    for (int i = 0; i < 8; ++i) len += sh.e.redi[i];
    __syncthreads();   // everyone done reading redi before LDS reuse

    // ---- split points: t_e ~0.25us (1-wave), t_m ~1.25us -> M = 9% of (len-1) ----
    const int M  = ((len - 1) * 9) / 100;          // mid segment steps (each)
    const int E1 = ((len - 1) - 2 * M + 1) >> 1;   // fwd steps
    const int q1 = E1;
    const int q2 = q1 + M;
    const int q3 = q2 + M;
    const int E2 = (len - 1) - q3;                 // bwd steps

    const float* emB = em + (size_t)b * SS * TT;

    if (isEnd) {
        // =================== END SEGMENTS: single-wave matvec chain ===================
        const int steps = isF ? q1 : E2;
        const int curF = steps & 1;                // final dbuf index (cur toggles each step)

        // init: fwd u0 = exp(start + em[0] - M0); bwd d_{len-1} = exp(end + em[len-1] - M0)
        if (t < 16) {
            const float* base = isF ? startt : endt;
            const float* emI  = emB + (isF ? 0 : (size_t)(len - 1) * TT);
            float a[8]; float mx = -1e30f;
            #pragma unroll
            for (int jj = 0; jj < 8; ++jj) {
                int j = t * 8 + jj;
                a[jj] = base[j] + emI[j];
                mx = fmaxf(mx, a[jj]);
            }
            mx = fmaxf(mx, __shfl_xor(mx, 1)); mx = fmaxf(mx, __shfl_xor(mx, 2));
            mx = fmaxf(mx, __shfl_xor(mx, 4)); mx = fmaxf(mx, __shfl_xor(mx, 8));
            union { __bf16 h[8]; uint4 v; } pk;
            #pragma unroll
            for (int jj = 0; jj < 8; ++jj) pk.h[jj] = (__bf16)__expf(a[jj] - mx);
            *(uint4*)&sh.e.uS[0][t * 8] = pk.v;
            if (t == 0) sh.e.Minit = mx;
        }
        __syncthreads();

        if (w == 0) {
            // Full A-frags in registers: 8 m-tiles x 4 k-tiles (128 VGPR).
            // fwd (A=E^T): af[mt][kt][jj] = E[32kt+8q+jj][16mt+c]
            // bwd (A=E):   af[mt][kt][jj] = E[16mt+c][32kt+8q+jj]
            bf16x8 af[8][4];
            #pragma unroll
            for (int mt = 0; mt < 8; ++mt) {
                #pragma unroll
                for (int kt = 0; kt < 4; ++kt) {
                    #pragma unroll
                    for (int jj = 0; jj < 8; ++jj) {
                        int row = isF ? (32 * kt + 8 * q + jj) : (16 * mt + c);
                        int col = isF ? (16 * mt + c) : (32 * kt + 8 * q + jj);
                        size_t idx = (size_t)row * TT + col;
                        af[mt][kt][jj] = mask_at(forb, mode, idx) ? (__bf16)0.f
                                                                  : (__bf16)__expf(trans[idx]);
                    }
                }
            }

            double Cd = (double)sh.e.Minit;
            float pending = 1.0f;
            int cur = 0;
            int rc = 0;

            // prefetch slot: em row -> exp -> bf16-packed scales (uint2 = rows r0..r3 of one mt)
            auto ldsc = [&](int k, int mi) -> uint2 {
                int kk = isF ? (1 + k) : (len - 2 - k);
                kk = kk < SS ? kk : SS - 1;
                kk = kk > 0 ? kk : 0;
                float4 e = *(const float4*)(emB + (size_t)kk * TT + 16 * mi + 4 * q);
                union { __bf16 h[4]; uint2 v; } u;
                u.h[0] = (__bf16)__expf(e.x); u.h[1] = (__bf16)__expf(e.y);
                u.h[2] = (__bf16)__expf(e.z); u.h[3] = (__bf16)__expf(e.w);
                return u.v;
            };

            // one step: 4 LDS b128 reads (broadcast) -> 32 MFMA -> scale -> pack -> 8 LDS b64 writes
            auto estep = [&](uint2 s0, uint2 s1, uint2 s2, uint2 s3,
                             uint2 s4, uint2 s5, uint2 s6, uint2 s7, bool scaleEm) {
                const uint2 sv[8] = {s0, s1, s2, s3, s4, s5, s6, s7};  // static idx only
                const __bf16* ub = &sh.e.uS[cur][0];

                f32x4 acc[8];
                #pragma unroll
                for (int mt = 0; mt < 8; ++mt) acc[mt] = (f32x4){0.f, 0.f, 0.f, 0.f};
                #pragma unroll
                for (int kt = 0; kt < 4; ++kt) {
                    bf16x8 bfk = *(const bf16x8*)(ub + 32 * kt + 8 * q);
                    #pragma unroll
                    for (int mt = 0; mt < 8; ++mt)
                        acc[mt] = __builtin_amdgcn_mfma_f32_16x16x32_bf16(af[mt][kt], bfk, acc[mt], 0, 0, 0);
                }

                ++rc;
                const bool ren = (rc == GRP);
                if (ren) rc = 0;
                const float pq = pending;

                float vmax = 0.f;
                __bf16* un = &sh.e.uS[cur ^ 1][0];
                #pragma unroll
                for (int mt = 0; mt < 8; ++mt) {
                    union { __bf16 h[4]; uint2 v; } su; su.v = sv[mt];
                    float s0f = scaleEm ? (float)su.h[0] : 1.0f;
                    float s1f = scaleEm ? (float)su.h[1] : 1.0f;
                    float s2f = scaleEm ? (float)su.h[2] : 1.0f;
                    float s3f = scaleEm ? (float)su.h[3] : 1.0f;
                    float v0 = acc[mt][0] * s0f * pq;
                    float v1 = acc[mt][1] * s1f * pq;
                    float v2 = acc[mt][2] * s2f * pq;
                    float v3 = acc[mt][3] * s3f * pq;
                    vmax = fmaxf(vmax, fmaxf(fmaxf(v0, v1), fmaxf(v2, v3)));
                    union { __bf16 h[4]; uint2 v; } pk;
                    pk.h[0] = (__bf16)v0; pk.h[1] = (__bf16)v1;
                    pk.h[2] = (__bf16)v2; pk.h[3] = (__bf16)v3;
                    if (c == 0) *(uint2*)(un + 16 * mt + 4 * q) = pk.v;
                }
                if (ren) {  // reduce over q only (all c identical)
                    vmax = fmaxf(vmax, __shfl_xor(vmax, 16));
                    vmax = fmaxf(vmax, __shfl_xor(vmax, 32));
                    pending = 1.0f / vmax;
                    Cd += (double)__logf(vmax);
                } else {
                    pending = 1.0f;
                }
                cur ^= 1;
            };

            // 2-unrolled loop, 2-step-deep em prefetch in NAMED slots (rule #20)
            uint2 sA0 = ldsc(0, 0), sA1 = ldsc(0, 1), sA2 = ldsc(0, 2), sA3 = ldsc(0, 3),
                  sA4 = ldsc(0, 4), sA5 = ldsc(0, 5), sA6 = ldsc(0, 6), sA7 = ldsc(0, 7);
            uint2 sB0 = ldsc(1, 0), sB1 = ldsc(1, 1), sB2 = ldsc(1, 2), sB3 = ldsc(1, 3),
                  sB4 = ldsc(1, 4), sB5 = ldsc(1, 5), sB6 = ldsc(1, 6), sB7 = ldsc(1, 7);
            int k = 0;
            while (k + 2 <= steps) {
                estep(sA0, sA1, sA2, sA3, sA4, sA5, sA6, sA7, isF || (k != steps - 1));
                sA0 = ldsc(k + 2, 0); sA1 = ldsc(k + 2, 1); sA2 = ldsc(k + 2, 2); sA3 = ldsc(k + 2, 3);
                sA4 = ldsc(k + 2, 4); sA5 = ldsc(k + 2, 5); sA6 = ldsc(k + 2, 6); sA7 = ldsc(k + 2, 7);
                estep(sB0, sB1, sB2, sB3, sB4, sB5, sB6, sB7, isF || (k + 1 != steps - 1));
                sB0 = ldsc(k + 3, 0); sB1 = ldsc(k + 3, 1); sB2 = ldsc(k + 3, 2); sB3 = ldsc(k + 3, 3);
                sB4 = ldsc(k + 3, 4); sB5 = ldsc(k + 3, 5); sB6 = ldsc(k + 3, 6); sB7 = ldsc(k + 3, 7);
                k += 2;
            }
            if (k < steps)
                estep(sA0, sA1, sA2, sA3, sA4, sA5, sA6, sA7, isF || (k != steps - 1));

            if (lane == 0) { CdW[(isF ? 0 : BB) + b] = Cd; pendW[(isF ? 0 : BB) + b] = pending; }
        }
        __syncthreads();   // uS[curF] now coherent for all waves

        // ---- dump state (fwd: alpha_q1 scaled; bwd: gamma_q3 scaled) ----
        if (t < TT) uMW[(size_t)(isF ? 0 : BB) * TT + (size_t)b * TT + t] = (float)sh.e.uS[curF][t];

        // ---- posterior path score (fwd blocks only; 512 threads strided) ----
        if (isF) {
            const int* tg = tags + (size_t)b * SS;
            double local = 0.0; int fcnt = 0;
            for (int kk = 1 + t; kk < len; kk += 512) {
                int tp = tg[kk - 1], tc = tg[kk];
                if (mask_at(forb, mode, (size_t)tp * TT + tc)) fcnt++;
                else local += (double)trans[tp * TT + tc];
                local += (double)emB[(size_t)kk * TT + tc];
            }
            if (t == 0) {
                local += (double)startt[tg[0]] + (double)emB[tg[0]];
                local += (double)endt[tg[len - 1]];
            }
            #pragma unroll
            for (int off = 32; off >= 1; off >>= 1) {
                local += __shfl_xor(local, off);
                fcnt  += __shfl_xor(fcnt, off);
            }
            if (lane == 0) { sh.e.redd[w] = local; sh.e.redc[w] = fcnt; }
            __syncthreads();
            if (t == 0) {
                double tot = 0.0; int fc = 0;
                #pragma unroll
                for (int i = 0; i < 8; ++i) { tot += sh.e.redd[i]; fc += sh.e.redc[i]; }
                postout[b] = tot - 100000.0 * (double)fc;
            }
        }
    } else {
        // =================== MID SEGMENTS (unchanged from round 9, proven) ===================
        const int wr = w >> 2;
        const int wc = w & 3;
        const int ks = half ? q2 : q1;     // steps consume em rows ks+1 .. ks+M
        const int steps = M;
        const int col0 = 32 * wc + c;
        const int col1 = col0 + 16;
        const int base0 = col0 * 128;
        const int base1 = col1 * 128;
        const int sw = (c & 7) << 3;
        const int rowq = 4 * q;

        // A = E^T: af[mi][kt][jj] = E[32kt+8q+jj][16*(4wr+mi)+c]
        bf16x8 af[4][4];
        #pragma unroll
        for (int mi = 0; mi < 4; ++mi) {
            #pragma unroll
            for (int kt = 0; kt < 4; ++kt) {
                #pragma unroll
                for (int jj = 0; jj < 8; ++jj) {
                    size_t idx = (size_t)(32 * kt + 8 * q + jj) * TT + (16 * (4 * wr + mi) + c);
                    af[mi][kt][jj] = mask_at(forb, mode, idx) ? (__bf16)0.f
                                                              : (__bf16)__expf(trans[idx]);
                }
            }
        }

        // identity init of T[0] (swizzled)
        for (int p = t; p < 8192; p += 512) {
            int n  = p >> 6;
            int k2 = (p & 63) * 2;
            unsigned int v = (k2 == n ? 0x3F80u : 0u) | (k2 + 1 == n ? 0x3F800000u : 0u);
            *(unsigned int*)&sh.m.T[0][n * 128 + (k2 ^ ((n & 7) << 3))] = v;
        }
        __syncthreads();

        double Cdc0 = 0.0, Cdc1 = 0.0;
        int cur = 0;
        int rc = 0;

        auto lde = [&](int s, int mi) -> float4 {
            int kk = ks + 1 + s; kk = kk < SS ? kk : SS - 1;
            return *(const float4*)(emB + (size_t)kk * TT + 16 * (4 * wr + mi) + rowq);
        };

        auto midstep = [&](float4 ev0, float4 ev1, float4 ev2, float4 ev3) {
            const float4 ev[4] = {ev0, ev1, ev2, ev3};   // static-index only below
            const __bf16* Tc = &sh.m.T[cur][0];
            bf16x8 bf0[4], bf1[4];
            #pragma unroll
            for (int kt = 0; kt < 4; ++kt) {
                int eo = (32 * kt + 8 * q) ^ sw;
                bf0[kt] = *(const bf16x8*)(Tc + base0 + eo);
                bf1[kt] = *(const bf16x8*)(Tc + base1 + eo);
            }

            bool ren;
            if (rc == GRP) { ren = true; rc = 0; } else ren = false;
            ++rc;

            float pend0 = 1.0f, pend1 = 1.0f;
            if (ren) {
                float m0 = 0.f, m1 = 0.f;
                #pragma unroll
                for (int kt = 0; kt < 4; ++kt) {
                    #pragma unroll
                    for (int jj = 0; jj < 8; ++jj) {
                        m0 = fmaxf(m0, (float)bf0[kt][jj]);
                        m1 = fmaxf(m1, (float)bf1[kt][jj]);
                    }
                }
                m0 = fmaxf(m0, __shfl_xor(m0, 16)); m0 = fmaxf(m0, __shfl_xor(m0, 32));
                m1 = fmaxf(m1, __shfl_xor(m1, 16)); m1 = fmaxf(m1, __shfl_xor(m1, 32));
                pend0 = 1.0f / m0; pend1 = 1.0f / m1;
                Cdc0 += (double)__logf(m0); Cdc1 += (double)__logf(m1);
            }

            f32x4 acc[4][2];
            #pragma unroll
            for (int mi = 0; mi < 4; ++mi) {
                acc[mi][0] = (f32x4){0.f, 0.f, 0.f, 0.f};
                acc[mi][1] = (f32x4){0.f, 0.f, 0.f, 0.f};
            }
            #pragma unroll
            for (int kt = 0; kt < 4; ++kt) {
                #pragma unroll
                for (int mi = 0; mi < 4; ++mi)
                    acc[mi][0] = __builtin_amdgcn_mfma_f32_16x16x32_bf16(af[mi][kt], bf0[kt], acc[mi][0], 0, 0, 0);
                #pragma unroll
                for (int mi = 0; mi < 4; ++mi)
                    acc[mi][1] = __builtin_amdgcn_mfma_f32_16x16x32_bf16(af[mi][kt], bf1[kt], acc[mi][1], 0, 0, 0);
            }

            __bf16* Tn = &sh.m.T[cur ^ 1][0];
            #pragma unroll
            for (int mi = 0; mi < 4; ++mi) {
                float s0 = __expf(ev[mi].x), s1 = __expf(ev[mi].y);
                float s2 = __expf(ev[mi].z), s3 = __expf(ev[mi].w);
                const int row = 16 * (4 * wr + mi) + rowq;
                const int eo = row ^ sw;
                union { __bf16 h[4]; uint2 u; } pk0, pk1;
                pk0.h[0] = (__bf16)(acc[mi][0][0] * s0 * pend0);
                pk0.h[1] = (__bf16)(acc[mi][0][1] * s1 * pend0);
                pk0.h[2] = (__bf16)(acc[mi][0][2] * s2 * pend0);
                pk0.h[3] = (__bf16)(acc[mi][0][3] * s3 * pend0);
                pk1.h[0] = (__bf16)(acc[mi][1][0] * s0 * pend1);
                pk1.h[1] = (__bf16)(acc[mi][1][1] * s1 * pend1);
                pk1.h[2] = (__bf16)(acc[mi][1][2] * s2 * pend1);
                pk1.h[3] = (__bf16)(acc[mi][1][3] * s3 * pend1);
                *(uint2*)(Tn + base0 + eo) = pk0.u;
                *(uint2*)(Tn + base1 + eo) = pk1.u;
            }
            wg_barrier_lds();
            cur ^= 1;
        };

        float4 eA0 = lde(0, 0), eA1 = lde(0, 1), eA2 = lde(0, 2), eA3 = lde(0, 3);
        float4 eB0 = lde(1, 0), eB1 = lde(1, 1), eB2 = lde(1, 2), eB3 = lde(1, 3);
        int s = 0;
        while (s + 2 <= steps) {
            midstep(eA0, eA1, eA2, eA3);
            eA0 = lde(s + 2, 0); eA1 = lde(s + 2, 1); eA2 = lde(s + 2, 2); eA3 = lde(s + 2, 3);
            midstep(eB0, eB1, eB2, eB3);
            eB0 = lde(s + 3, 0); eB1 = lde(s + 3, 1); eB2 = lde(s + 3, 2); eB3 = lde(s + 3, 3);
            s += 2;
        }
        if (s < steps) midstep(eA0, eA1, eA2, eA3);

        __syncthreads();
        if (wr == 0 && q == 0) {
            lsW[(size_t)seg * 128 + col0] = Cdc0;
            lsW[(size_t)seg * 128 + col1] = Cdc1;
        }
        for (int p = t; p < 8192; p += 512) {
            int n  = p >> 6;
            int k2 = (p & 63) * 2;
            unsigned int v = *(const unsigned int*)&sh.m.T[cur][n * 128 + (k2 ^ ((n & 7) << 3))];
            *(unsigned int*)&Tws[(size_t)seg * 16384 + (size_t)n * 128 + k2] = v;
        }
    }
}

// ---- combine: z[b] = Cf + lpf + K1 + K2 + Cb + lpb + log( sum_i s_i*gamma_i ) ----
__global__ __launch_bounds__(128) void comb_kernel(
    const double* __restrict__ CdW, const float* __restrict__ pendW,
    const float* __restrict__ uMW, const double* __restrict__ lsW,
    const unsigned short* __restrict__ Tws, double* __restrict__ zarr)
{
    const int b = blockIdx.x, i = threadIdx.x;
    __shared__ double wv[128];
    __shared__ double red[128];

    double lsA = lsW[(size_t)(2 * b) * 128 + i];
    float  xf  = uMW[(size_t)b * 128 + i];
    double a1  = (xf > 0.f) ? lsA + log((double)xf) : -1e300;
    red[i] = a1; __syncthreads();
    for (int sdel = 64; sdel >= 1; sdel >>= 1) {
        if (i < sdel) red[i] = fmax(red[i], red[i + sdel]);
        __syncthreads();
    }
    double K1 = red[0]; __syncthreads();
    wv[i] = (xf > 0.f) ? exp(a1 - K1) : 0.0; __syncthreads();

    const unsigned short* TA = Tws + (size_t)(2 * b) * 16384;
    double y = 0.0;
    for (int n = 0; n < 128; ++n) {
        unsigned int u = ((unsigned int)TA[(size_t)n * 128 + i]) << 16;
        y += (double)__uint_as_float(u) * wv[n];
    }
    __syncthreads();

    double lsB = lsW[(size_t)(2 * b + 1) * 128 + i];
    double a2  = (y > 0.0) ? lsB + log(y) : -1e300;
    red[i] = a2; __syncthreads();
    for (int sdel = 64; sdel >= 1; sdel >>= 1) {
        if (i < sdel) red[i] = fmax(red[i], red[i + sdel]);
        __syncthreads();
    }
    double K2 = red[0]; __syncthreads();
    wv[i] = (y > 0.0) ? exp(a2 - K2) : 0.0; __syncthreads();

    const unsigned short* TB = Tws + (size_t)(2 * b + 1) * 16384;
    double s = 0.0;
    for (int n = 0; n < 128; ++n) {
        unsigned int u = ((unsigned int)TB[(size_t)n * 128 + i]) << 16;
        s += (double)__uint_as_float(u) * wv[n];
    }
    double g = (double)uMW[(size_t)(BB + b) * 128 + i];
    red[i] = s * g; __syncthreads();
    for (int sdel = 64; sdel >= 1; sdel >>= 1) {
        if (i < sdel) red[i] += red[i + sdel];
        __syncthreads();
    }
    if (i == 0) {
        zarr[b] = CdW[b] + log((double)pendW[b])
                + CdW[BB + b] + log((double)pendW[BB + b])
                + K1 + K2 + log(red[0]);
    }
}

// ---- nll = mean(post) - mean(z) ----
__global__ void fin_kernel(const double* __restrict__ z, const double* __restrict__ post,
                           float* __restrict__ out) {
    int t = threadIdx.x; // 64 threads, 1 wave
    double pv = post[t];
    double zv = z[t];
    #pragma unroll
    for (int off = 32; off >= 1; off >>= 1) {
        pv += __shfl_xor(pv, off);
        zv += __shfl_xor(zv, off);
    }
    if (t == 0) out[0] = (float)((pv - zv) / (double)BB);
}

extern "C" void kernel_launch(void* const* d_in, const int* in_sizes, int n_in,
                              void* d_out, int out_size, void* d_ws, size_t ws_size,
                              hipStream_t stream) {
    const float* em     = (const float*)d_in[0];
    const void*  maskp  = d_in[1];
    const int*   tags   = (const int*)d_in[2];
    const void*  forb   = d_in[3];
    const float* trans  = (const float*)d_in[4];
    const float* startt = (const float*)d_in[5];
    const float* endt   = (const float*)d_in[6];

    // workspace: ~4.4 MB (layout proven in round 3)
    double* post  = (double*)d_ws;                     // 64
    double* zarr  = post + BB;                         // 64
    double* CdW   = zarr + BB;                         // 128 (fwd | bwd)
    double* lsW   = CdW + 2 * BB;                      // 128 segs x 128 cols
    float*  pendW = (float*)(lsW + 128 * 128);         // 128
    float*  uMW   = pendW + 2 * BB;                    // 128 x 128 (fwd states | bwd states)
    unsigned short* Tws = (unsigned short*)(uMW + 128 * 128); // 128 segs x 128 x 128 bf16

    scan_kernel<<<4 * BB, 512, 0, stream>>>(em, maskp, tags, forb, trans, startt, endt,
                                            CdW, pendW, uMW, lsW, Tws, post);
    comb_kernel<<<BB, 128, 0, stream>>>(CdW, pendW, uMW, lsW, Tws, zarr);
    fin_kernel<<<1, 64, 0, stream>>>(zarr, post, (float*)d_out);
}